// Round 10
// baseline (44396.429 us; speedup 1.0000x reference)
//
#include <hip/hip_runtime.h>
#include <cmath>

// Problem constants (from reference): B=64, T=512, I=512, H=1024, L=2
#define B_  64
#define T_  512
#define I_  512
#define H_  1024
#define TI_ (T_ * I_)   // x row pitch per batch (floats)
#define TH_ (T_ * H_)   // h1 row pitch per batch (floats)
#define CK  256         // K-chunk staged per LDS buffer (group quantum)
#define CP  65          // row pitch (pad +1 -> conflict-free lane=b reads)
#define NBLK 256
#define NTHR 256
#define LDS_BYTES (2 * CK * CP * 4)

// ---- coherent primitives (agent scope => sc1 => bypass per-XCD L2) ---------
__device__ __forceinline__ void stcg(float* p, float v)
{
  __hip_atomic_store(p, v, __ATOMIC_RELAXED, __HIP_MEMORY_SCOPE_AGENT);
}

// issue 4 coherent 16B loads (no wait) -- results valid only after vmcnt(0)
__device__ __forceinline__ void issue4(const float* p0, const float* p1,
                                       const float* p2, const float* p3,
                                       float4& f0, float4& f1, float4& f2, float4& f3)
{
  asm volatile(
    "global_load_dwordx4 %0, %4, off sc0 sc1\n\t"
    "global_load_dwordx4 %1, %5, off sc0 sc1\n\t"
    "global_load_dwordx4 %2, %6, off sc0 sc1\n\t"
    "global_load_dwordx4 %3, %7, off sc0 sc1"
    : "=&v"(f0), "=&v"(f1), "=&v"(f2), "=&v"(f3)
    : "v"(p0), "v"(p1), "v"(p2), "v"(p3));
}

// ---- zero-fence distributed flag barrier (validated in r8) -----------------
__device__ __forceinline__ void publish(unsigned* flags, int bid, unsigned seq)
{
  asm volatile("s_waitcnt vmcnt(0)" ::: "memory");
  __syncthreads();
  if (threadIdx.x == 0)
    __hip_atomic_store(&flags[bid], seq, __ATOMIC_RELAXED, __HIP_MEMORY_SCOPE_AGENT);
}

__device__ __forceinline__ void waitall(unsigned* flags, unsigned target, bool acq)
{
  const int tid = threadIdx.x;
  if (tid < NBLK) {
    while (__hip_atomic_load(&flags[tid], __ATOMIC_RELAXED, __HIP_MEMORY_SCOPE_AGENT) < target)
      __builtin_amdgcn_s_sleep(1);
  }
  __syncthreads();
  if (acq) {
    if (tid == 0)
      (void)__hip_atomic_load(&flags[0], __ATOMIC_ACQUIRE, __HIP_MEMORY_SCOPE_AGENT);
    __syncthreads();
  }
}

// ---- fma over a 256-k chunk: 3 weight rows, input from LDS [k][b] ----------
__device__ __forceinline__ void chunk_fma256(const float* cb, int b,
                                             const float* wr, const float* wz, const float* wn,
                                             float& aR, float& aZ, float& aN)
{
#pragma unroll 8
  for (int k4 = 0; k4 < CK / 4; ++k4) {
    float4 WR = *(const float4*)(wr + k4 * 4);
    float4 WZ = *(const float4*)(wz + k4 * 4);
    float4 WN = *(const float4*)(wn + k4 * 4);
    float v0 = cb[(k4 * 4 + 0) * CP + b];
    float v1 = cb[(k4 * 4 + 1) * CP + b];
    float v2 = cb[(k4 * 4 + 2) * CP + b];
    float v3 = cb[(k4 * 4 + 3) * CP + b];
    aR = fmaf(WR.x, v0, aR); aZ = fmaf(WZ.x, v0, aZ); aN = fmaf(WN.x, v0, aN);
    aR = fmaf(WR.y, v1, aR); aZ = fmaf(WZ.y, v1, aZ); aN = fmaf(WN.y, v1, aN);
    aR = fmaf(WR.z, v2, aR); aZ = fmaf(WZ.z, v2, aZ); aN = fmaf(WN.z, v2, aN);
    aR = fmaf(WR.w, v3, aR); aZ = fmaf(WZ.w, v3, aZ); aN = fmaf(WN.w, v3, aN);
  }
}

// 16 scalar LDS stores: 64-k sub-block transposed to [k][b], pitch CP
__device__ __forceinline__ void stage_store(float* cbw, int q4, int r0,
                                            const float4& pf0, const float4& pf1,
                                            const float4& pf2, const float4& pf3)
{
  cbw[(q4 + 0) * CP + (r0 +  0)] = pf0.x;
  cbw[(q4 + 1) * CP + (r0 +  0)] = pf0.y;
  cbw[(q4 + 2) * CP + (r0 +  0)] = pf0.z;
  cbw[(q4 + 3) * CP + (r0 +  0)] = pf0.w;
  cbw[(q4 + 0) * CP + (r0 + 16)] = pf1.x;
  cbw[(q4 + 1) * CP + (r0 + 16)] = pf1.y;
  cbw[(q4 + 2) * CP + (r0 + 16)] = pf1.z;
  cbw[(q4 + 3) * CP + (r0 + 16)] = pf1.w;
  cbw[(q4 + 0) * CP + (r0 + 32)] = pf2.x;
  cbw[(q4 + 1) * CP + (r0 + 32)] = pf2.y;
  cbw[(q4 + 2) * CP + (r0 + 32)] = pf2.z;
  cbw[(q4 + 3) * CP + (r0 + 32)] = pf2.w;
  cbw[(q4 + 0) * CP + (r0 + 48)] = pf3.x;
  cbw[(q4 + 1) * CP + (r0 + 48)] = pf3.y;
  cbw[(q4 + 2) * CP + (r0 + 48)] = pf3.z;
  cbw[(q4 + 3) * CP + (r0 + 48)] = pf3.w;
}

// Process nchunks 256-k chunks from src (per-batch pitch `pitch`).
// Per chunk: 16 float4/thread held in registers, issued a full chunk ahead;
// latency is paid once per chunk and covered by the previous chunk's fma.
template <bool COH>
__device__ __forceinline__ void phase256(float* smem, int nchunks,
                                         const float* src, size_t pitch,
                                         const float* wr, const float* wz, const float* wn,
                                         float& aR, float& aZ, float& aN,
                                         int q4, int r0, int b)
{
  float4 a0, a1, a2, a3, b0, b1, b2, b3, c0, c1, c2, c3, d0, d1, d2, d3;

#define LOADSUB(gA, gB, gC, gD, base)                                          \
  if constexpr (COH) {                                                         \
    issue4((base) + (size_t)(r0 +  0) * pitch,                                 \
           (base) + (size_t)(r0 + 16) * pitch,                                 \
           (base) + (size_t)(r0 + 32) * pitch,                                 \
           (base) + (size_t)(r0 + 48) * pitch, gA, gB, gC, gD);                \
  } else {                                                                     \
    gA = *(const float4*)((base) + (size_t)(r0 +  0) * pitch);                 \
    gB = *(const float4*)((base) + (size_t)(r0 + 16) * pitch);                 \
    gC = *(const float4*)((base) + (size_t)(r0 + 32) * pitch);                 \
    gD = *(const float4*)((base) + (size_t)(r0 + 48) * pitch);                 \
  }

#define LOADCHUNK(cidx) {                                                      \
    const float* pb_ = src + (size_t)(cidx) * CK + q4;                         \
    LOADSUB(a0, a1, a2, a3, pb_ +   0)                                         \
    LOADSUB(b0, b1, b2, b3, pb_ +  64)                                         \
    LOADSUB(c0, c1, c2, c3, pb_ + 128)                                         \
    LOADSUB(d0, d1, d2, d3, pb_ + 192)                                         \
  }

  LOADCHUNK(0);
  for (int c = 0; c < nchunks; ++c) {
    if constexpr (COH) {
      asm volatile("s_waitcnt vmcnt(0)" ::: "memory");
      __builtin_amdgcn_sched_barrier(0);
    }
    float* cbw = smem + (c & 1) * (CK * CP);
    stage_store(cbw +   0 * CP, q4, r0, a0, a1, a2, a3);
    stage_store(cbw +  64 * CP, q4, r0, b0, b1, b2, b3);
    stage_store(cbw + 128 * CP, q4, r0, c0, c1, c2, c3);
    stage_store(cbw + 192 * CP, q4, r0, d0, d1, d2, d3);
    if (c + 1 < nchunks) LOADCHUNK(c + 1);   // in flight across the fma below
    __syncthreads();
    chunk_fma256(smem + (c & 1) * (CK * CP), b,
                 wr + c * CK, wz + c * CK, wn + c * CK, aR, aZ, aN);
  }
#undef LOADCHUNK
#undef LOADSUB
}

__global__ void __launch_bounds__(NTHR)
gru_fused(const float* __restrict__ x,
          const float* __restrict__ wih0, const float* __restrict__ whh0,
          const float* __restrict__ bih0, const float* __restrict__ bhh0,
          const float* __restrict__ wih1, const float* __restrict__ whh1,
          const float* __restrict__ bih1, const float* __restrict__ bhh1,
          float* __restrict__ h1, float* __restrict__ hb0, float* __restrict__ hb1,
          unsigned* __restrict__ flags, float* __restrict__ out)
{
  extern __shared__ float smem[];   // 2 x [CK][CP] = 133120 B

  const int tid = threadIdx.x;
  const int b   = tid & 63;                                   // lane = batch row
  const int jj  = __builtin_amdgcn_readfirstlane(tid >> 6);   // wave id, uniform
  const int bid = blockIdx.x;
  const int j   = bid * 4 + jj;                               // owned h column
  const int q4  = (tid & 15) * 4;                             // staging k offset
  const int r0  = tid >> 4;                                   // staging base row

  for (int layer = 0; layer < 2; ++layer) {
    const int Ki  = layer ? H_ : I_;
    const int NCX = Ki / CK;        // x-part chunks (2 or 4)
    const int NCH = H_ / CK;        // h-part chunks (4)

    const float* wih = layer ? wih1 : wih0;
    const float* whh = layer ? whh1 : whh0;
    const float* bih = layer ? bih1 : bih0;
    const float* bhh = layer ? bhh1 : bhh0;

    const float* wxr = wih + (size_t)(0 * H_ + j) * Ki;
    const float* wxz = wih + (size_t)(1 * H_ + j) * Ki;
    const float* wxn = wih + (size_t)(2 * H_ + j) * Ki;
    const float* whr = whh + (size_t)(0 * H_ + j) * H_;
    const float* whz = whh + (size_t)(1 * H_ + j) * H_;
    const float* whn = whh + (size_t)(2 * H_ + j) * H_;

    const float bR  = bih[j] + bhh[j];
    const float bZ  = bih[H_ + j] + bhh[H_ + j];
    const float bXN = bih[2 * H_ + j];
    const float bHN = bhh[2 * H_ + j];

    float hreg = 0.0f;  // h(b, j) lives in a register for the whole scan

    for (int t = 0; t < T_; ++t) {
      float accR = bR, accZ = bZ, accXN = bXN, accHN = bHN;

      // layer transition: ONE acquire so layer-1 can read h1 with cached loads
      if (layer == 1 && t == 0) waitall(flags, (unsigned)T_, /*acq=*/true);

      // ---- x-phase: independent of h(t-1); overlaps other blocks' publishes.
      const float* xsrc = layer ? (h1 + (size_t)t * H_) : (x + (size_t)t * I_);
      const size_t xpit = layer ? (size_t)TH_ : (size_t)TI_;
      phase256<false>(smem, NCX, xsrc, xpit, wxr, wxz, wxn,
                      accR, accZ, accXN, q4, r0, b);

      // ---- h-phase: needs all blocks' h(t-1); coherent group-pipelined loads
      if (t > 0) {
        waitall(flags, (unsigned)(layer * T_ + t), /*acq=*/false);
        const float* hsrc = layer ? ((t & 1) ? hb0 : hb1)
                                  : (h1 + (size_t)(t - 1) * H_);
        const size_t hpit = layer ? (size_t)H_ : (size_t)TH_;
        phase256<true>(smem, NCH, hsrc, hpit, whr, whz, whn,
                       accR, accZ, accHN, q4, r0, b);
      }

      // gates
      const float r = 1.0f / (1.0f + expf(-accR));
      const float z = 1.0f / (1.0f + expf(-accZ));
      const float n = tanhf(accXN + r * accHN);
      const float hnew = (1.0f - z) * n + z * hreg;
      hreg = hnew;

      // h store: coherent (sc1) -> lands at IF$; no dirty L2 line created.
      if (layer == 0) {
        stcg(&h1[(size_t)b * TH_ + (size_t)t * H_ + j], hnew);
      } else {
        stcg(&((t & 1) ? hb1 : hb0)[b * H_ + j], hnew);
        if (t == T_ - 1) out[b * H_ + j] = hnew;   // cached; end-of-kernel flush
      }

      if (!(layer == 1 && t == T_ - 1))
        publish(flags, bid, (unsigned)(layer * T_ + t + 1));
    }
  }
}

extern "C" void kernel_launch(void* const* d_in, const int* in_sizes, int n_in,
                              void* d_out, int out_size, void* d_ws, size_t ws_size,
                              hipStream_t stream)
{
  const float* x    = (const float*)d_in[0];
  const float* wih0 = (const float*)d_in[1];
  const float* whh0 = (const float*)d_in[2];
  const float* bih0 = (const float*)d_in[3];
  const float* bhh0 = (const float*)d_in[4];
  const float* wih1 = (const float*)d_in[5];
  const float* whh1 = (const float*)d_in[6];
  const float* bih1 = (const float*)d_in[7];
  const float* bhh1 = (const float*)d_in[8];
  float* out = (float*)d_out;

  // workspace: h1 (B*T*H) | hb0 (B*H) | hb1 (B*H) | flags[NBLK]
  float* h1  = (float*)d_ws;
  float* hb0 = h1 + (size_t)B_ * T_ * H_;
  float* hb1 = hb0 + (size_t)B_ * H_;
  unsigned* flags = (unsigned*)(hb1 + (size_t)B_ * H_);

  // allow >64KB dynamic LDS (host-side attribute; not a stream op)
  hipFuncSetAttribute((const void*)gru_fused,
                      hipFuncAttributeMaxDynamicSharedMemorySize, LDS_BYTES);

  // flags must start at 0 (harness poisons ws with 0xAA)
  hipMemsetAsync(flags, 0, NBLK * sizeof(unsigned), stream);

  void* args[] = { (void*)&x,
                   (void*)&wih0, (void*)&whh0, (void*)&bih0, (void*)&bhh0,
                   (void*)&wih1, (void*)&whh1, (void*)&bih1, (void*)&bhh1,
                   (void*)&h1, (void*)&hb0, (void*)&hb1, (void*)&flags, (void*)&out };

  hipLaunchCooperativeKernel((const void*)gru_fused,
                             dim3(NBLK), dim3(NTHR), args, LDS_BYTES, stream);
}